// Round 5
// baseline (267.188 us; speedup 1.0000x reference)
//
#include <hip/hip_runtime.h>
#include <hip/hip_fp16.h>

#define NN 50000
#define NE 800000
#define D 128
#define NBLK ((NN + 255) / 256)   // 196 blocks over nodes

typedef __attribute__((ext_vector_type(8))) short bf16x8;
typedef __attribute__((ext_vector_type(4))) float f32x4;

static __device__ __forceinline__ unsigned short f2bf(float f) {
    unsigned u = __builtin_bit_cast(unsigned, f);
    unsigned r = (u + 0x7fffu + ((u >> 16) & 1u)) >> 16;   // RN-even
    return (unsigned short)r;
}
static __device__ __forceinline__ float bf2f(unsigned short h) {
    unsigned u = ((unsigned)h) << 16;
    return __builtin_bit_cast(float, u);
}

// ---------------- CSR build ----------------
__global__ __launch_bounds__(256) void k_zero_cnt(int* __restrict__ cnt) {
    int i = blockIdx.x * 256 + threadIdx.x;
    if (i < NN) cnt[i] = 0;
}

__global__ __launch_bounds__(256) void k_count(const int* __restrict__ dst, int* __restrict__ cnt) {
    int e = blockIdx.x * 256 + threadIdx.x;
    if (e < NE) atomicAdd(&cnt[dst[e]], 1);
}

__global__ __launch_bounds__(256) void k_scan_partial(const int* __restrict__ cnt, int* __restrict__ blockSums) {
    __shared__ int s[256];
    int t = threadIdx.x;
    int i = blockIdx.x * 256 + t;
    s[t] = (i < NN) ? cnt[i] : 0;
    __syncthreads();
    for (int off = 128; off > 0; off >>= 1) {
        if (t < off) s[t] += s[t + off];
        __syncthreads();
    }
    if (t == 0) blockSums[blockIdx.x] = s[0];
}

__global__ __launch_bounds__(256) void k_scan_blocks(int* __restrict__ blockSums, int* __restrict__ row_ptr) {
    __shared__ int s[256];
    int t = threadIdx.x;
    int v = (t < NBLK) ? blockSums[t] : 0;
    s[t] = v;
    __syncthreads();
    for (int off = 1; off < 256; off <<= 1) {
        int y = (t >= off) ? s[t - off] : 0;
        __syncthreads();
        s[t] += y;
        __syncthreads();
    }
    if (t < NBLK) blockSums[t] = s[t] - v;  // exclusive block offsets
    if (t == 0) row_ptr[NN] = NE;
}

// also computes dinv = rsqrt(deg+1)
__global__ __launch_bounds__(256) void k_scan_final(const int* __restrict__ cnt, const int* __restrict__ blockOffs,
                                                    int* __restrict__ row_ptr, int* __restrict__ cursor,
                                                    float* __restrict__ dinv) {
    __shared__ int s[256];
    int t = threadIdx.x;
    int i = blockIdx.x * 256 + t;
    int v = (i < NN) ? cnt[i] : 0;
    s[t] = v;
    __syncthreads();
    for (int off = 1; off < 256; off <<= 1) {
        int y = (t >= off) ? s[t - off] : 0;
        __syncthreads();
        s[t] += y;
        __syncthreads();
    }
    if (i < NN) {
        int excl = s[t] - v + blockOffs[blockIdx.x];
        row_ptr[i] = excl;
        cursor[i] = excl;
        dinv[i] = rsqrtf((float)v + 1.0f);
    }
}

__global__ __launch_bounds__(256) void k_fill(const int* __restrict__ src, const int* __restrict__ dst,
                                              int* __restrict__ cursor, unsigned short* __restrict__ csr) {
    int e = blockIdx.x * 256 + threadIdx.x;
    if (e < NE) {
        int pos = atomicAdd(&cursor[dst[e]], 1);
        csr[pos] = (unsigned short)src[e];
    }
}

// ---------------- W prep: fp32 [k][n] -> swizzled bf16 hi/lo images of W^T [n][k] ----------------
__global__ __launch_bounds__(256) void k_prepw(const float* __restrict__ W1, const float* __restrict__ W2,
                                               char* __restrict__ img1, char* __restrict__ img2) {
    int b = blockIdx.x;
    const float* W = (b < 64) ? W1 : W2;
    char* img = (b < 64) ? img1 : img2;
    int e = (b & 63) * 256 + threadIdx.x;  // 0..16383
    int k = e >> 7, n = e & 127;
    float f = W[e];
    unsigned short hi = f2bf(f);
    float rem = f - bf2f(hi);
    unsigned short lo = f2bf(rem);
    unsigned off = (unsigned)((n << 8) + (k << 1)) ^ (unsigned)((n & 7) << 4);
    *(unsigned short*)(img + off) = hi;
    *(unsigned short*)(img + 32768 + off) = lo;
}

// ---------------- MFMA GEMM: H[M,128] = act(A[M,128]) @ W[128,128], bf16x3 split, fp16 out ----------------
template <bool RELU_IN>
__global__ __launch_bounds__(256) void k_mgemm(const float* __restrict__ A, const char* __restrict__ wimg,
                                               __half* __restrict__ H) {
    __shared__ char lds[65536];
    const int t = threadIdx.x;

    {   // stage both swizzled bf16 images (byte-identical copy)
        const float4* gv = (const float4*)wimg;
        float4* lv = (float4*)lds;
#pragma unroll
        for (int i = 0; i < 16; ++i) lv[i * 256 + t] = gv[i * 256 + t];
    }
    __syncthreads();

    const int lane = t & 63;
    const int wv = t >> 6;
    const int r0 = blockIdx.x * 64 + wv * 16;
    const int rl = lane & 15;              // A row in strip / C col
    const int g = lane >> 4;               // k-group 0..3
    int arow = r0 + rl;
    if (arow >= NN) arow = NN - 1;
    const float* ar = A + (size_t)arow * D + g * 8;

    f32x4 acc[8];
#pragma unroll
    for (int j = 0; j < 8; ++j) acc[j] = (f32x4){0.f, 0.f, 0.f, 0.f};

#pragma unroll
    for (int ks = 0; ks < 4; ++ks) {
        float av[8];
        float4 p0 = *(const float4*)(ar + ks * 32);
        float4 p1 = *(const float4*)(ar + ks * 32 + 4);
        av[0] = p0.x; av[1] = p0.y; av[2] = p0.z; av[3] = p0.w;
        av[4] = p1.x; av[5] = p1.y; av[6] = p1.z; av[7] = p1.w;
        bf16x8 ah, al;
#pragma unroll
        for (int i = 0; i < 8; ++i) {
            float a = RELU_IN ? fmaxf(av[i], 0.f) : av[i];
            unsigned short h = f2bf(a);
            ah[i] = (short)h;
            al[i] = (short)f2bf(a - bf2f(h));
        }
        const int kofs = (ks * 32 + g * 8) << 1;
#pragma unroll
        for (int j = 0; j < 8; ++j) {
            int n = j * 16 + rl;
            unsigned off = (unsigned)((n << 8) + kofs) ^ (unsigned)((n & 7) << 4);
            bf16x8 bh = *(const bf16x8*)(lds + off);
            bf16x8 bl = *(const bf16x8*)(lds + 32768 + off);
            acc[j] = __builtin_amdgcn_mfma_f32_16x16x32_bf16(ah, bh, acc[j], 0, 0, 0);
            acc[j] = __builtin_amdgcn_mfma_f32_16x16x32_bf16(ah, bl, acc[j], 0, 0, 0);
            acc[j] = __builtin_amdgcn_mfma_f32_16x16x32_bf16(al, bh, acc[j], 0, 0, 0);
        }
    }

    // C/D: col = lane&15, row = (lane>>4)*4 + reg
#pragma unroll
    for (int j = 0; j < 8; ++j) {
#pragma unroll
        for (int i = 0; i < 4; ++i) {
            int row = r0 + g * 4 + i;
            if (row < NN) H[(size_t)row * D + j * 16 + rl] = __float2half(acc[j][i]);
        }
    }
}

// ---------------- pull aggregation: one wave per node, 16 lanes per edge-row ----------------
// lane = g*16 + rl; group g handles edges beg+g, beg+g+4, ...; lane's dims = rl*8..rl*8+7
__global__ __launch_bounds__(256) void k_pull(const __half* __restrict__ H, const float* __restrict__ dinv,
                                              const float* __restrict__ b, const int* __restrict__ row_ptr,
                                              const unsigned short* __restrict__ csr, float* __restrict__ out) {
    int wid = (blockIdx.x * 256 + threadIdx.x) >> 6;
    int lane = threadIdx.x & 63;
    int node = __builtin_amdgcn_readfirstlane(wid);  // wave-uniform
    int rl = lane & 15;
    int g = lane >> 4;

    float dd = dinv[node];   // wave-uniform scalar

    float2 a0 = {0.f, 0.f}, a1 = {0.f, 0.f}, a2 = {0.f, 0.f}, a3 = {0.f, 0.f};

    int beg = row_ptr[node];
    int end = row_ptr[node + 1];
    for (int i = beg + g; i < end; i += 4) {
        int s = csr[i];                        // u16, broadcast within 16-lane group
        float c = dinv[s] * dd;                // exact coef, L2-hot gather
        float4 raw = *(const float4*)(H + (size_t)s * D + rl * 8);  // 8 halves
        const __half2* hh = (const __half2*)&raw;
        float2 f0 = __half22float2(hh[0]);
        float2 f1 = __half22float2(hh[1]);
        float2 f2 = __half22float2(hh[2]);
        float2 f3 = __half22float2(hh[3]);
        a0.x = fmaf(f0.x, c, a0.x); a0.y = fmaf(f0.y, c, a0.y);
        a1.x = fmaf(f1.x, c, a1.x); a1.y = fmaf(f1.y, c, a1.y);
        a2.x = fmaf(f2.x, c, a2.x); a2.y = fmaf(f2.y, c, a2.y);
        a3.x = fmaf(f3.x, c, a3.x); a3.y = fmaf(f3.y, c, a3.y);
    }

    // butterfly-reduce the 4 lane-groups (xor 16, 32); all lanes end with full sums
    float v[8] = {a0.x, a0.y, a1.x, a1.y, a2.x, a2.y, a3.x, a3.y};
#pragma unroll
    for (int i = 0; i < 8; ++i) {
        v[i] += __shfl_xor(v[i], 16);
        v[i] += __shfl_xor(v[i], 32);
    }

    if (g == 0) {
        float s2 = dd * dd;
        float4 raw = *(const float4*)(H + (size_t)node * D + rl * 8);
        const __half2* hh = (const __half2*)&raw;
        float2 s0 = __half22float2(hh[0]);
        float2 s1 = __half22float2(hh[1]);
        float2 s2v = __half22float2(hh[2]);
        float2 s3 = __half22float2(hh[3]);
        float4 b0 = ((const float4*)b)[rl * 2];
        float4 b1 = ((const float4*)b)[rl * 2 + 1];
        float4 r0, r1;
        r0.x = fmaf(s0.x, s2, v[0] + b0.x);
        r0.y = fmaf(s0.y, s2, v[1] + b0.y);
        r0.z = fmaf(s1.x, s2, v[2] + b0.z);
        r0.w = fmaf(s1.y, s2, v[3] + b0.w);
        r1.x = fmaf(s2v.x, s2, v[4] + b1.x);
        r1.y = fmaf(s2v.y, s2, v[5] + b1.y);
        r1.z = fmaf(s3.x, s2, v[6] + b1.z);
        r1.w = fmaf(s3.y, s2, v[7] + b1.w);
        float4* op = (float4*)(out + (size_t)node * D + rl * 8);
        op[0] = r0;
        op[1] = r1;
    }
}

extern "C" void kernel_launch(void* const* d_in, const int* in_sizes, int n_in,
                              void* d_out, int out_size, void* d_ws, size_t ws_size,
                              hipStream_t stream) {
    const float* x  = (const float*)d_in[0];
    const int*   ei = (const int*)d_in[1];
    const float* W1 = (const float*)d_in[2];
    const float* b1 = (const float*)d_in[3];
    const float* W2 = (const float*)d_in[4];
    const float* b2 = (const float*)d_in[5];
    float* out = (float*)d_out;

    const int* src = ei;
    const int* dst = ei + NE;

    char* ws = (char*)d_ws;
    int*    cnt       = (int*)   (ws + 0);        // 200000 B
    int*    row_ptr   = (int*)   (ws + 204800);   // NN+1 ints
    int*    cursor    = (int*)   (ws + 409600);
    int*    blockSums = (int*)   (ws + 614400);   // 784 B
    float*  dinv      = (float*) (ws + 615424);   // 200000 B
    char*   wimg1     = (char*)  (ws + 819200);   // 64 KB
    char*   wimg2     = (char*)  (ws + 884736);   // 64 KB
    unsigned short* csr = (unsigned short*)(ws + 950272);  // NE u16 = 1.6 MB -> ends 2550272
    __half* h         = (__half*)(ws + 2550784);  // NN*D fp16 = 12.8 MB (16B aligned)

    const int nBlkEdge = (NE + 255) / 256;   // 3125
    const int nBlkGemm = (NN + 63) / 64;     // 782
    const int nBlkPull = NN / 4;             // 12500

    // CSR build + norm + weight prep
    k_zero_cnt<<<NBLK, 256, 0, stream>>>(cnt);
    k_count<<<nBlkEdge, 256, 0, stream>>>(dst, cnt);
    k_scan_partial<<<NBLK, 256, 0, stream>>>(cnt, blockSums);
    k_scan_blocks<<<1, 256, 0, stream>>>(blockSums, row_ptr);
    k_scan_final<<<NBLK, 256, 0, stream>>>(cnt, blockSums, row_ptr, cursor, dinv);
    k_fill<<<nBlkEdge, 256, 0, stream>>>(src, dst, cursor, csr);
    k_prepw<<<128, 256, 0, stream>>>(W1, W2, wimg1, wimg2);

    // layer 1  (d_out doubles as the layer-1 aggregation buffer, fp32)
    k_mgemm<false><<<nBlkGemm, 256, 0, stream>>>(x, wimg1, h);
    k_pull<<<nBlkPull, 256, 0, stream>>>(h, dinv, b1, row_ptr, csr, out);

    // layer 2 (ReLU folded into GEMM A-fragment load)
    k_mgemm<true><<<nBlkGemm, 256, 0, stream>>>(out, wimg2, h);
    k_pull<<<nBlkPull, 256, 0, stream>>>(h, dinv, b2, row_ptr, csr, out);
}

// Round 6
// 238.278 us; speedup vs baseline: 1.1213x; 1.1213x over previous
//
#include <hip/hip_runtime.h>
#include <hip/hip_fp16.h>

#define NN 50000
#define NE 800000
#define D 128
#define NBLK ((NN + 255) / 256)   // 196 blocks over nodes

typedef __attribute__((ext_vector_type(8))) short bf16x8;
typedef __attribute__((ext_vector_type(4))) float f32x4;

static __device__ __forceinline__ unsigned short f2bf(float f) {
    unsigned u = __builtin_bit_cast(unsigned, f);
    unsigned r = (u + 0x7fffu + ((u >> 16) & 1u)) >> 16;   // RN-even
    return (unsigned short)r;
}
static __device__ __forceinline__ float bf2f(unsigned short h) {
    unsigned u = ((unsigned)h) << 16;
    return __builtin_bit_cast(float, u);
}

// ---------------- CSR build ----------------
__global__ __launch_bounds__(256) void k_zero_cnt(int* __restrict__ cnt) {
    int i = blockIdx.x * 256 + threadIdx.x;
    if (i < NN) cnt[i] = 0;
}

// histogram + per-edge rank (rank store is coalesced fire-and-forget)
__global__ __launch_bounds__(256) void k_count(const int* __restrict__ dst, int* __restrict__ cnt,
                                               int* __restrict__ rank) {
    int e = blockIdx.x * 256 + threadIdx.x;
    if (e < NE) rank[e] = atomicAdd(&cnt[dst[e]], 1);
}

__global__ __launch_bounds__(256) void k_scan_partial(const int* __restrict__ cnt, int* __restrict__ blockSums) {
    __shared__ int s[256];
    int t = threadIdx.x;
    int i = blockIdx.x * 256 + t;
    s[t] = (i < NN) ? cnt[i] : 0;
    __syncthreads();
    for (int off = 128; off > 0; off >>= 1) {
        if (t < off) s[t] += s[t + off];
        __syncthreads();
    }
    if (t == 0) blockSums[blockIdx.x] = s[0];
}

__global__ __launch_bounds__(256) void k_scan_blocks(int* __restrict__ blockSums, int* __restrict__ row_ptr) {
    __shared__ int s[256];
    int t = threadIdx.x;
    int v = (t < NBLK) ? blockSums[t] : 0;
    s[t] = v;
    __syncthreads();
    for (int off = 1; off < 256; off <<= 1) {
        int y = (t >= off) ? s[t - off] : 0;
        __syncthreads();
        s[t] += y;
        __syncthreads();
    }
    if (t < NBLK) blockSums[t] = s[t] - v;  // exclusive block offsets
    if (t == 0) row_ptr[NN] = NE;
}

// exclusive scan -> row_ptr; also dinv = rsqrt(deg+1)
__global__ __launch_bounds__(256) void k_scan_final(const int* __restrict__ cnt, const int* __restrict__ blockOffs,
                                                    int* __restrict__ row_ptr, float* __restrict__ dinv) {
    __shared__ int s[256];
    int t = threadIdx.x;
    int i = blockIdx.x * 256 + t;
    int v = (i < NN) ? cnt[i] : 0;
    s[t] = v;
    __syncthreads();
    for (int off = 1; off < 256; off <<= 1) {
        int y = (t >= off) ? s[t - off] : 0;
        __syncthreads();
        s[t] += y;
        __syncthreads();
    }
    if (i < NN) {
        row_ptr[i] = s[t] - v + blockOffs[blockIdx.x];
        dinv[i] = rsqrtf((float)v + 1.0f);
    }
}

// no atomics: pos = row_ptr[dst] + rank
__global__ __launch_bounds__(256) void k_fill(const int* __restrict__ src, const int* __restrict__ dst,
                                              const int* __restrict__ rank, const int* __restrict__ row_ptr,
                                              unsigned short* __restrict__ csr) {
    int e = blockIdx.x * 256 + threadIdx.x;
    if (e < NE) {
        int d = dst[e];
        csr[row_ptr[d] + rank[e]] = (unsigned short)src[e];
    }
}

// ---------------- W prep: fp32 [k][n] -> swizzled bf16 hi/lo images of W^T [n][k] ----------------
__global__ __launch_bounds__(256) void k_prepw(const float* __restrict__ W1, const float* __restrict__ W2,
                                               char* __restrict__ img1, char* __restrict__ img2) {
    int b = blockIdx.x;
    const float* W = (b < 64) ? W1 : W2;
    char* img = (b < 64) ? img1 : img2;
    int e = (b & 63) * 256 + threadIdx.x;  // 0..16383
    int k = e >> 7, n = e & 127;
    float f = W[e];
    unsigned short hi = f2bf(f);
    float rem = f - bf2f(hi);
    unsigned short lo = f2bf(rem);
    unsigned off = (unsigned)((n << 8) + (k << 1)) ^ (unsigned)((n & 7) << 4);
    *(unsigned short*)(img + off) = hi;
    *(unsigned short*)(img + 32768 + off) = lo;
}

// ---------------- MFMA GEMM: H[M,128] = act(A[M,128]) @ W[128,128], bf16x3 split, fp16 out ----------------
template <bool RELU_IN>
__global__ __launch_bounds__(256) void k_mgemm(const float* __restrict__ A, const char* __restrict__ wimg,
                                               __half* __restrict__ H) {
    __shared__ char lds[65536];
    const int t = threadIdx.x;

    {   // stage both swizzled bf16 images (byte-identical copy)
        const float4* gv = (const float4*)wimg;
        float4* lv = (float4*)lds;
#pragma unroll
        for (int i = 0; i < 16; ++i) lv[i * 256 + t] = gv[i * 256 + t];
    }
    __syncthreads();

    const int lane = t & 63;
    const int wv = t >> 6;
    const int r0 = blockIdx.x * 64 + wv * 16;
    const int rl = lane & 15;              // A row in strip / C col
    const int g = lane >> 4;               // k-group 0..3
    int arow = r0 + rl;
    if (arow >= NN) arow = NN - 1;
    const float* ar = A + (size_t)arow * D + g * 8;

    f32x4 acc[8];
#pragma unroll
    for (int j = 0; j < 8; ++j) acc[j] = (f32x4){0.f, 0.f, 0.f, 0.f};

#pragma unroll
    for (int ks = 0; ks < 4; ++ks) {
        float av[8];
        float4 p0 = *(const float4*)(ar + ks * 32);
        float4 p1 = *(const float4*)(ar + ks * 32 + 4);
        av[0] = p0.x; av[1] = p0.y; av[2] = p0.z; av[3] = p0.w;
        av[4] = p1.x; av[5] = p1.y; av[6] = p1.z; av[7] = p1.w;
        bf16x8 ah, al;
#pragma unroll
        for (int i = 0; i < 8; ++i) {
            float a = RELU_IN ? fmaxf(av[i], 0.f) : av[i];
            unsigned short h = f2bf(a);
            ah[i] = (short)h;
            al[i] = (short)f2bf(a - bf2f(h));
        }
        const int kofs = (ks * 32 + g * 8) << 1;
#pragma unroll
        for (int j = 0; j < 8; ++j) {
            int n = j * 16 + rl;
            unsigned off = (unsigned)((n << 8) + kofs) ^ (unsigned)((n & 7) << 4);
            bf16x8 bh = *(const bf16x8*)(lds + off);
            bf16x8 bl = *(const bf16x8*)(lds + 32768 + off);
            acc[j] = __builtin_amdgcn_mfma_f32_16x16x32_bf16(ah, bh, acc[j], 0, 0, 0);
            acc[j] = __builtin_amdgcn_mfma_f32_16x16x32_bf16(ah, bl, acc[j], 0, 0, 0);
            acc[j] = __builtin_amdgcn_mfma_f32_16x16x32_bf16(al, bh, acc[j], 0, 0, 0);
        }
    }

    // C/D: col = lane&15, row = (lane>>4)*4 + reg
#pragma unroll
    for (int j = 0; j < 8; ++j) {
#pragma unroll
        for (int i = 0; i < 4; ++i) {
            int row = r0 + g * 4 + i;
            if (row < NN) H[(size_t)row * D + j * 16 + rl] = __float2half(acc[j][i]);
        }
    }
}

// ---------------- pull aggregation: one wave per node, 16 lanes per edge-row, 2-deep unroll ----------------
__global__ __launch_bounds__(256) void k_pull(const __half* __restrict__ H, const float* __restrict__ dinv,
                                              const float* __restrict__ b, const int* __restrict__ row_ptr,
                                              const unsigned short* __restrict__ csr, float* __restrict__ out) {
    int wid = (blockIdx.x * 256 + threadIdx.x) >> 6;
    int lane = threadIdx.x & 63;
    int node = __builtin_amdgcn_readfirstlane(wid);  // wave-uniform
    int rl = lane & 15;
    int g = lane >> 4;

    float dd = dinv[node];   // wave-uniform scalar

    float2 a0 = {0.f, 0.f}, a1 = {0.f, 0.f}, a2 = {0.f, 0.f}, a3 = {0.f, 0.f};
    float2 c0b = {0.f, 0.f}, c1b = {0.f, 0.f}, c2b = {0.f, 0.f}, c3b = {0.f, 0.f};

    int beg = row_ptr[node];
    int end = row_ptr[node + 1];
    for (int i = beg + g; i < end; i += 8) {
        int i1 = i + 4;
        bool ok = i1 < end;
        int s0 = csr[i];
        int s1 = csr[ok ? i1 : i];
        float c0 = dinv[s0] * dd;
        float c1 = ok ? dinv[s1] * dd : 0.f;
        float4 raw0 = *(const float4*)(H + (size_t)s0 * D + rl * 8);
        float4 raw1 = *(const float4*)(H + (size_t)s1 * D + rl * 8);
        const __half2* h0 = (const __half2*)&raw0;
        const __half2* h1 = (const __half2*)&raw1;
        float2 f0 = __half22float2(h0[0]);
        float2 f1 = __half22float2(h0[1]);
        float2 f2 = __half22float2(h0[2]);
        float2 f3 = __half22float2(h0[3]);
        a0.x = fmaf(f0.x, c0, a0.x); a0.y = fmaf(f0.y, c0, a0.y);
        a1.x = fmaf(f1.x, c0, a1.x); a1.y = fmaf(f1.y, c0, a1.y);
        a2.x = fmaf(f2.x, c0, a2.x); a2.y = fmaf(f2.y, c0, a2.y);
        a3.x = fmaf(f3.x, c0, a3.x); a3.y = fmaf(f3.y, c0, a3.y);
        float2 g0 = __half22float2(h1[0]);
        float2 g1 = __half22float2(h1[1]);
        float2 g2 = __half22float2(h1[2]);
        float2 g3 = __half22float2(h1[3]);
        c0b.x = fmaf(g0.x, c1, c0b.x); c0b.y = fmaf(g0.y, c1, c0b.y);
        c1b.x = fmaf(g1.x, c1, c1b.x); c1b.y = fmaf(g1.y, c1, c1b.y);
        c2b.x = fmaf(g2.x, c1, c2b.x); c2b.y = fmaf(g2.y, c1, c2b.y);
        c3b.x = fmaf(g3.x, c1, c3b.x); c3b.y = fmaf(g3.y, c1, c3b.y);
    }
    a0.x += c0b.x; a0.y += c0b.y;
    a1.x += c1b.x; a1.y += c1b.y;
    a2.x += c2b.x; a2.y += c2b.y;
    a3.x += c3b.x; a3.y += c3b.y;

    // butterfly-reduce the 4 lane-groups (xor 16, 32)
    float v[8] = {a0.x, a0.y, a1.x, a1.y, a2.x, a2.y, a3.x, a3.y};
#pragma unroll
    for (int i = 0; i < 8; ++i) {
        v[i] += __shfl_xor(v[i], 16);
        v[i] += __shfl_xor(v[i], 32);
    }

    if (g == 0) {
        float s2 = dd * dd;
        float4 raw = *(const float4*)(H + (size_t)node * D + rl * 8);
        const __half2* hh = (const __half2*)&raw;
        float2 s0 = __half22float2(hh[0]);
        float2 s1 = __half22float2(hh[1]);
        float2 s2v = __half22float2(hh[2]);
        float2 s3 = __half22float2(hh[3]);
        float4 b0 = ((const float4*)b)[rl * 2];
        float4 b1 = ((const float4*)b)[rl * 2 + 1];
        float4 r0, r1;
        r0.x = fmaf(s0.x, s2, v[0] + b0.x);
        r0.y = fmaf(s0.y, s2, v[1] + b0.y);
        r0.z = fmaf(s1.x, s2, v[2] + b0.z);
        r0.w = fmaf(s1.y, s2, v[3] + b0.w);
        r1.x = fmaf(s2v.x, s2, v[4] + b1.x);
        r1.y = fmaf(s2v.y, s2, v[5] + b1.y);
        r1.z = fmaf(s3.x, s2, v[6] + b1.z);
        r1.w = fmaf(s3.y, s2, v[7] + b1.w);
        float4* op = (float4*)(out + (size_t)node * D + rl * 8);
        op[0] = r0;
        op[1] = r1;
    }
}

extern "C" void kernel_launch(void* const* d_in, const int* in_sizes, int n_in,
                              void* d_out, int out_size, void* d_ws, size_t ws_size,
                              hipStream_t stream) {
    const float* x  = (const float*)d_in[0];
    const int*   ei = (const int*)d_in[1];
    const float* W1 = (const float*)d_in[2];
    const float* b1 = (const float*)d_in[3];
    const float* W2 = (const float*)d_in[4];
    const float* b2 = (const float*)d_in[5];
    float* out = (float*)d_out;

    const int* src = ei;
    const int* dst = ei + NE;

    char* ws = (char*)d_ws;
    int*    cnt       = (int*)   (ws + 0);         // 200000 B
    int*    row_ptr   = (int*)   (ws + 204800);    // NN+1 ints
    int*    blockSums = (int*)   (ws + 409600);    // 784 B
    float*  dinv      = (float*) (ws + 410624);    // 200000 B -> ends 610624
    char*   wimg1     = (char*)  (ws + 614400);    // 64 KB
    char*   wimg2     = (char*)  (ws + 679936);    // 64 KB
    int*    rank      = (int*)   (ws + 745472);    // NE ints = 3.2 MB -> ends 3945472
    unsigned short* csr = (unsigned short*)(ws + 3945472);  // NE u16 = 1.6 MB -> ends 5545472
    __half* h         = (__half*)(ws + 5545472);   // NN*D fp16 = 12.8 MB

    const int nBlkEdge = (NE + 255) / 256;   // 3125
    const int nBlkGemm = (NN + 63) / 64;     // 782
    const int nBlkPull = NN / 4;             // 12500

    // CSR build + norm + weight prep
    k_zero_cnt<<<NBLK, 256, 0, stream>>>(cnt);
    k_count<<<nBlkEdge, 256, 0, stream>>>(dst, cnt, rank);
    k_scan_partial<<<NBLK, 256, 0, stream>>>(cnt, blockSums);
    k_scan_blocks<<<1, 256, 0, stream>>>(blockSums, row_ptr);
    k_scan_final<<<NBLK, 256, 0, stream>>>(cnt, blockSums, row_ptr, dinv);
    k_fill<<<nBlkEdge, 256, 0, stream>>>(src, dst, rank, row_ptr, csr);
    k_prepw<<<128, 256, 0, stream>>>(W1, W2, wimg1, wimg2);

    // layer 1  (d_out doubles as the layer-1 aggregation buffer, fp32)
    k_mgemm<false><<<nBlkGemm, 256, 0, stream>>>(x, wimg1, h);
    k_pull<<<nBlkPull, 256, 0, stream>>>(h, dinv, b1, row_ptr, csr, out);

    // layer 2 (ReLU folded into GEMM A-fragment load)
    k_mgemm<true><<<nBlkGemm, 256, 0, stream>>>(out, wimg2, h);
    k_pull<<<nBlkPull, 256, 0, stream>>>(h, dinv, b2, row_ptr, csr, out);
}